// Round 1
// baseline (359.193 us; speedup 1.0000x reference)
//
#include <hip/hip_runtime.h>
#include <cstddef>

// BoardModel: B=16384 samples.
// out layout: d_out[0 .. B*96)  = concat([xf(32), a_mean(32), b2(32)]) per sample
//             d_out[B*96 .. )   = padded board (3,22,12) per sample
//
// Math notes (verified against reference):
//  - MHA has kv seq-len 1 -> softmax over singleton axis == 1.0 exactly, so
//    a.mean(1) = out_proj_w @ v + out_proj_b with v = in_proj_w[64:96] @ b2 + in_proj_b[64:96].
//    emb / positional encoding / Q / K projections are dead code.
//  - piece scatter always lands in-bounds for this input distribution, but we
//    implement the exact 'drop' semantics anyway.

#define BATCH 16384
#define SPB   16            // samples per block
#define NBLK  (BATCH / SPB)

// scratch region offsets (floats). Peak usage:
//   chunk phase : SBE 2*1248 + C1 2*1584 = 5664
//   tail  phase : C2 16*225 + P2 16*49 + C3 16*65 + B2 16*33 + V 16*33 = 6480
#define SCR_SBE(s,j)   scr[(s)*1248 + (j)]                 // zero-extended board (3,26,16)
#define SCR_C1(s,j)    scr[2496 + (s)*1584 + (j)]          // conv1 out (6,22,12)
#define SCR_C2(s,i)    scr[(s)*225 + (i)]                  // conv2 out (16,7,2) flat o*14+p, pad 225
#define SCR_P2(s,i)    scr[3600 + (s)*49 + (i)]            // pool2 (16,3) flat, pad 49
#define SCR_C3(s,i)    scr[4384 + (s)*65 + (i)]            // conv3 out (64), pad 65
#define SCR_B2(s,i)    scr[5424 + (s)*33 + (i)]            // fc1 out (32), pad 33
#define SCR_V(s,i)     scr[5952 + (s)*33 + (i)]            // v-proj (32), pad 33

__global__ __launch_bounds__(256, 3)
void board_model_kernel(const int* __restrict__ t,           // (B,232)
                        const int* __restrict__ piece_table, // (8,4,4,4)
                        const float* __restrict__ w1, const float* __restrict__ b1,   // (6,3,5,5),(6)
                        const float* __restrict__ w2, const float* __restrict__ b2w,  // (16,6,5,5),(16)
                        const float* __restrict__ w3, const float* __restrict__ b3,   // (64,16,3,1),(64)
                        const float* __restrict__ wf1, const float* __restrict__ bf1, // (32,64),(32)
                        const float* __restrict__ fcw, const float* __restrict__ fcb, // (32,8),(32)
                        const float* __restrict__ ipw, const float* __restrict__ ipb, // (96,32),(96)
                        const float* __restrict__ opw, const float* __restrict__ opb, // (32,32),(32)
                        float* __restrict__ out,              // (B,96)
                        float* __restrict__ out_board)        // (B,3,22,12)
{
  __shared__ float P1s[SPB * 396];   // pool1 out (6,11,6) per sample, persistent
  __shared__ float scr[6480];        // overlaid scratch

  const int tid = threadIdx.x;
  const int bb  = blockIdx.x * SPB;

  // ---------------- per-chunk (2 samples): board build, conv1, pool1 ----------------
  for (int ck = 0; ck < SPB / 2; ++ck) {
    const int s0 = ck * 2;

    // Fill zero-extended board SBE (3,26,16); interior [2..24)x[2..14) is the
    // padded board (22x12): bottom row / left / right cols = 1.0, ch0 = content.
    for (int i = tid; i < 2 * 1248; i += 256) {
      int s = i / 1248, j = i - s * 1248;
      int ch = j / 416, jr = j - ch * 416;
      int rr = jr >> 4, cc = jr & 15;
      float v = 0.f;
      if (rr >= 2 && rr < 24 && cc >= 2 && cc < 14) {
        int r = rr - 2, c = cc - 2;                 // padded-board coords
        if (r == 21 || c == 0 || c == 11) v = 1.f;  // pad = 1.0
        else if (ch == 0)
          v = (float)t[(size_t)(bb + s0 + s) * 232 + 22 + r * 10 + (c - 1)];
      }
      SCR_SBE(s, j) = v;
    }
    __syncthreads();

    // Piece scatter: 4 cells x 2 samples. idx = stable argsort(1-pieces)[:4]
    // == indices of the (exactly 4) ones in row-major order; fallback mimics
    // argsort exactly if fewer ones.
    if (tid < 8) {
      int s = tid >> 2, ci = tid & 3;
      const int* tr = t + (size_t)(bb + s0 + s) * 232;
      const int* pt = piece_table + (tr[8] * 4 + tr[4]) * 16;
      int sel = -1, n1 = 0;
      for (int j = 0; j < 16; ++j) { if (pt[j]) { if (n1 == ci) sel = j; n1++; } }
      if (sel < 0) {
        int n0 = 0;
        for (int j = 0; j < 16; ++j) if (!pt[j]) { if (n0 == ci - n1) { sel = j; break; } n0++; }
      }
      int cy = sel >> 2, cx = sel & 3;
      int x  = cx + tr[1] - 2;
      int y  = cy + tr[2];
      int ny = y + tr[3];
      if (y >= 0 && ny >= 0) {                       // reference mask
        if (y  < 21 && x >= 0 && x < 10) SCR_SBE(s, 1 * 416 + (y  + 2) * 16 + (x + 3)) = 1.f;
        if (ny < 21 && x >= 0 && x < 10) SCR_SBE(s, 2 * 416 + (ny + 2) * 16 + (x + 3)) = 1.f;
      }
    }
    __syncthreads();

    // Write padded board (second output), reading SBE interior.
    for (int i = tid; i < 2 * 792; i += 256) {
      int s = i / 792, j = i - s * 792;
      int ch = j / 264, jr = j - ch * 264;
      int r = jr / 12, c = jr - r * 12;
      out_board[(size_t)(bb + s0 + s) * 792 + j] =
          SCR_SBE(s, ch * 416 + (r + 2) * 16 + (c + 2));
    }

    // conv1 + relu: thread = (sample, position), 6 channel accs in regs.
    // Weight index is wave-uniform -> s_load (SMEM pipe, free).
    for (int slot = tid; slot < 2 * 264; slot += 256) {
      int s = slot / 264, p = slot - s * 264;
      int r = p / 12, c = p - r * 12;
      float acc[6];
#pragma unroll
      for (int o = 0; o < 6; ++o) acc[o] = b1[o];
      for (int ic = 0; ic < 3; ++ic)
        for (int kr = 0; kr < 5; ++kr) {
          const float* row = &scr[s * 1248 + ic * 416 + (r + kr) * 16 + c];
          float xv[5];
#pragma unroll
          for (int kc = 0; kc < 5; ++kc) xv[kc] = row[kc];
#pragma unroll
          for (int kc = 0; kc < 5; ++kc)
#pragma unroll
            for (int o = 0; o < 6; ++o)
              acc[o] += xv[kc] * w1[((o * 3 + ic) * 5 + kr) * 5 + kc];
        }
#pragma unroll
      for (int o = 0; o < 6; ++o)
        SCR_C1(s, (o * 22 + r) * 12 + c) = fmaxf(acc[o], 0.f);
    }
    __syncthreads();

    // pool1 -> persistent P1s
    for (int i = tid; i < 2 * 396; i += 256) {
      int s = i / 396, j = i - s * 396;
      int o = j / 66, jr = j - o * 66;
      int r = jr / 6, c = jr - r * 6;
      float v = 0.25f * (SCR_C1(s, (o * 22 + 2 * r) * 12 + 2 * c)
                       + SCR_C1(s, (o * 22 + 2 * r) * 12 + 2 * c + 1)
                       + SCR_C1(s, (o * 22 + 2 * r + 1) * 12 + 2 * c)
                       + SCR_C1(s, (o * 22 + 2 * r + 1) * 12 + 2 * c + 1));
      P1s[(s0 + s) * 396 + j] = v;
    }
    __syncthreads();
  }

  // ---------------- conv2 + relu: thread = (sample, position), 16 accs ----------------
  if (tid < SPB * 14) {
    int s = tid / 14, p = tid - s * 14;
    int r = p >> 1, c = p & 1;
    float acc[16];
#pragma unroll
    for (int o = 0; o < 16; ++o) acc[o] = b2w[o];
    const float* pin = &P1s[s * 396];
    for (int ic = 0; ic < 6; ++ic)
      for (int kr = 0; kr < 5; ++kr) {
        float xv[5];
#pragma unroll
        for (int kc = 0; kc < 5; ++kc) xv[kc] = pin[ic * 66 + (r + kr) * 6 + (c + kc)];
#pragma unroll
        for (int kc = 0; kc < 5; ++kc)
#pragma unroll
          for (int o = 0; o < 16; ++o)
            acc[o] += xv[kc] * w2[((o * 6 + ic) * 5 + kr) * 5 + kc];
      }
#pragma unroll
    for (int o = 0; o < 16; ++o)
      SCR_C2(s, o * 14 + p) = fmaxf(acc[o], 0.f);
  }
  __syncthreads();

  // pool2: (16,7,2) -> (16,3,1); crops row 6.
  for (int i = tid; i < SPB * 48; i += 256) {
    int jj = i >> 4, s = i & 15;
    int o = jj / 3, r = jj - o * 3;
    float v = 0.25f * (SCR_C2(s, o * 14 + (2 * r) * 2 + 0)
                     + SCR_C2(s, o * 14 + (2 * r) * 2 + 1)
                     + SCR_C2(s, o * 14 + (2 * r + 1) * 2 + 0)
                     + SCR_C2(s, o * 14 + (2 * r + 1) * 2 + 1));
    SCR_P2(s, jj) = v;
  }
  __syncthreads();

  // conv3 + relu: out[o] = b3[o] + sum_{k<48} P2[k]*w3[o*48+k]
  for (int i = tid; i < SPB * 64; i += 256) {
    int o = i >> 4, s = i & 15;
    float acc = b3[o];
#pragma unroll
    for (int k = 0; k < 48; ++k)
      acc += SCR_P2(s, k) * w3[o * 48 + k];
    SCR_C3(s, o) = fmaxf(acc, 0.f);
  }
  __syncthreads();

  // fc1 + relu -> b2; also third output slice.
  for (int i = tid; i < SPB * 32; i += 256) {
    int j = i >> 4, s = i & 15;
    float acc = bf1[j];
#pragma unroll
    for (int k = 0; k < 64; ++k)
      acc += SCR_C3(s, k) * wf1[j * 64 + k];
    acc = fmaxf(acc, 0.f);
    SCR_B2(s, j) = acc;
    out[(size_t)(bb + s) * 96 + 64 + j] = acc;
  }
  __syncthreads();

  // v = in_proj_w[64:96] @ b2 + in_proj_b[64:96]
  for (int i = tid; i < SPB * 32; i += 256) {
    int j = i >> 4, s = i & 15;
    float acc = ipb[64 + j];
#pragma unroll
    for (int k = 0; k < 32; ++k)
      acc += SCR_B2(s, k) * ipw[(64 + j) * 32 + k];
    SCR_V(s, j) = acc;
  }
  __syncthreads();

  // a.mean(1) = out_proj_w @ v + out_proj_b  (softmax over singleton == 1)
  for (int i = tid; i < SPB * 32; i += 256) {
    int j = i >> 4, s = i & 15;
    float acc = opb[j];
#pragma unroll
    for (int k = 0; k < 32; ++k)
      acc += SCR_V(s, k) * opw[j * 32 + k];
    out[(size_t)(bb + s) * 96 + 32 + j] = acc;
  }

  // xf = relu(t[:, :8] @ fc_w.T + fc_b)
  for (int i = tid; i < SPB * 32; i += 256) {
    int j = i >> 4, s = i & 15;
    const int* tr = t + (size_t)(bb + s) * 232;
    float acc = fcb[j];
#pragma unroll
    for (int k = 0; k < 8; ++k)
      acc += (float)tr[k] * fcw[j * 8 + k];
    out[(size_t)(bb + s) * 96 + j] = fmaxf(acc, 0.f);
  }
}

extern "C" void kernel_launch(void* const* d_in, const int* in_sizes, int n_in,
                              void* d_out, int out_size, void* d_ws, size_t ws_size,
                              hipStream_t stream) {
  const int*   t   = (const int*)d_in[0];
  const int*   pt  = (const int*)d_in[1];
  const float* w1  = (const float*)d_in[2];
  const float* b1  = (const float*)d_in[3];
  const float* w2  = (const float*)d_in[4];
  const float* b2w = (const float*)d_in[5];
  const float* w3  = (const float*)d_in[6];
  const float* b3  = (const float*)d_in[7];
  const float* wf1 = (const float*)d_in[8];
  const float* bf1 = (const float*)d_in[9];
  const float* fcw = (const float*)d_in[10];
  const float* fcb = (const float*)d_in[11];
  // d_in[12] = emb : dead (softmax over singleton axis)
  const float* ipw = (const float*)d_in[13];
  const float* ipb = (const float*)d_in[14];
  const float* opw = (const float*)d_in[15];
  const float* opb = (const float*)d_in[16];

  float* out       = (float*)d_out;
  float* out_board = out + (size_t)BATCH * 96;

  hipLaunchKernelGGL(board_model_kernel, dim3(NBLK), dim3(256), 0, stream,
                     t, pt, w1, b1, w2, b2w, w3, b3, wf1, bf1, fcw, fcb,
                     ipw, ipb, opw, opb, out, out_board);
}

// Round 2
// 352.813 us; speedup vs baseline: 1.0181x; 1.0181x over previous
//
#include <hip/hip_runtime.h>
#include <cstddef>

// BoardModel: B=16384. out = [xf(32), a_mean(32), b2(32)] per sample, then board (3,22,12).
// MHA is degenerate (kv len 1 -> softmax==1): a.mean = out_proj(in_proj[64:96] @ b2 + b).
//
// Structure: 4 samples/block (1 per wave). Phase A: per-wave board build + board-out
// (no cross-wave deps). Barrier. Phase B: block-cooperative fused conv1+pool1
// (264 positions on 256 threads; remainder 8 positions = 32 conv cells on wave 0,
// shfl-pooled). Barrier. Phase C: whole tail on wave 0 (weight indices wave-uniform
// everywhere -> scalar loads). SBE row stride 18 (banks spread; even cols -> float2).

#define BATCH 16384
#define SPB   4
#define NBLK  (BATCH / SPB)
#define SS    1804   // per-sample scratch floats: SBE 3*26*18=1404 @0, P1 6*66=396 @1404.
                     // Tail overlays SBE: C2 192 @0, P2 48 @192, C3 64 @240, B2 32 @304, V 32 @336.

__global__ __launch_bounds__(256, 5)
void board_model_kernel(const int* __restrict__ t,           // (B,232)
                        const int* __restrict__ piece_table, // (8,4,4,4)
                        const float* __restrict__ w1, const float* __restrict__ b1,
                        const float* __restrict__ w2, const float* __restrict__ b2w,
                        const float* __restrict__ w3, const float* __restrict__ b3,
                        const float* __restrict__ wf1, const float* __restrict__ bf1,
                        const float* __restrict__ fcw, const float* __restrict__ fcb,
                        const float* __restrict__ ipw, const float* __restrict__ ipb,
                        const float* __restrict__ opw, const float* __restrict__ opb,
                        float* __restrict__ out,              // (B,96)
                        float* __restrict__ out_board)        // (B,3,22,12)
{
  __shared__ __align__(16) float scr[SPB * SS];

  const int tid  = threadIdx.x;
  const int lane = tid & 63;
  const int wv   = tid >> 6;          // wave id == sample slot in phase A
  const int bb   = blockIdx.x * SPB;

  // ---------------- Phase A: per-wave board build + board output ----------------
  {
    float* W = &scr[wv * SS];
    const int* tr = t + (size_t)(bb + wv) * 232;

    // zero SBE (1404 floats) as float4 (SS*4 % 16 == 0 -> aligned)
    float4* W4 = (float4*)W;
    for (int i = lane; i < 351; i += 64) W4[i] = float4{0.f, 0.f, 0.f, 0.f};

    // content: board row r (0..20), col b (0..9) -> SBE[0][r+2][b+5]
    for (int i = lane; i < 210; i += 64) {
      int r = i / 10, b = i - r * 10;
      W[(r + 2) * 18 + b + 5] = (float)tr[22 + i];
    }

    // pad ones: padded row 21 (rr=23, cc 4..15), col0 (cc=4), col11 (cc=15), all 3 ch
    for (int i = lane; i < 162; i += 64) {
      int ch = i / 54, k = i - ch * 54;
      int rr, cc;
      if (k < 12)      { rr = 23;         cc = k + 4; }
      else if (k < 33) { rr = k - 12 + 2; cc = 4; }
      else             { rr = k - 33 + 2; cc = 15; }
      W[ch * 468 + rr * 18 + cc] = 1.f;
    }

    // piece scatter: lanes 0..3 each one cell (writes ch1 @ y and ch2 @ ny)
    if (lane < 4) {
      const int* pt = piece_table + (tr[8] * 4 + tr[4]) * 16;
      int sel = -1, n1 = 0;
#pragma unroll
      for (int j = 0; j < 16; ++j) { if (pt[j]) { if (n1 == lane) sel = j; ++n1; } }
      if (sel < 0) {
        int n0 = 0, want = lane - n1;
#pragma unroll
        for (int j = 0; j < 16; ++j) if (!pt[j]) { if (n0 == want) { sel = j; break; } ++n0; }
      }
      int cy = sel >> 2, cx = sel & 3;
      int x  = cx + tr[1] - 2;
      int y  = cy + tr[2];
      int ny = y + tr[3];
      if (y >= 0 && ny >= 0) {
        if (y  >= 0 && y  < 21 && x >= 0 && x < 10) W[468 + (y  + 2) * 18 + x + 5] = 1.f;
        if (ny >= 0 && ny < 21 && x >= 0 && x < 10) W[936 + (ny + 2) * 18 + x + 5] = 1.f;
      }
    }
    __builtin_amdgcn_wave_barrier();   // keep DS program order (in-wave LDS is in-order)

    // board output: board[ch][r][c] = SBE[ch][r+2][c+4]; vec4 over c (12%4==0)
    float* ob = out_board + (size_t)(bb + wv) * 792;
    for (int v = lane; v < 198; v += 64) {
      int j0 = v * 4;
      int ch = j0 / 264, rem = j0 - ch * 264;
      int r = rem / 12, c = rem - r * 12;
      const float* src = &W[ch * 468 + (r + 2) * 18 + c + 4];
      float4 val{src[0], src[1], src[2], src[3]};
      *(float4*)(ob + j0) = val;
    }
  }
  __syncthreads();

  // ---------------- Phase B: fused conv1+relu+pool1, block-cooperative ----------------
  {
    // main: thread t -> pool position g = t (0..255 of 264); q = g/66, p = g%66
    int g = tid;
    int q = g / 66, p = g - q * 66;
    int r = p / 6, c = p - r * 6;
    const float* Wq = &scr[q * SS];
    float acc[2][2][6];
#pragma unroll
    for (int i = 0; i < 2; ++i)
#pragma unroll
      for (int j = 0; j < 2; ++j)
#pragma unroll
        for (int o = 0; o < 6; ++o) acc[i][j][o] = b1[o];

    for (int ic = 0; ic < 3; ++ic) {
      const float* base = Wq + ic * 468 + (2 * r) * 18 + (2 * c + 2);
      float w[6][6];
#pragma unroll
      for (int u = 0; u < 6; ++u) {
        float2 a0 = *(const float2*)(base + u * 18 + 0);
        float2 a1 = *(const float2*)(base + u * 18 + 2);
        float2 a2 = *(const float2*)(base + u * 18 + 4);
        w[u][0] = a0.x; w[u][1] = a0.y; w[u][2] = a1.x;
        w[u][3] = a1.y; w[u][4] = a2.x; w[u][5] = a2.y;
      }
#pragma unroll
      for (int ky = 0; ky < 5; ++ky)
#pragma unroll
        for (int kx = 0; kx < 5; ++kx) {
#pragma unroll
          for (int i = 0; i < 2; ++i)
#pragma unroll
            for (int j = 0; j < 2; ++j) {
              float xv = w[i + ky][j + kx];
#pragma unroll
              for (int o = 0; o < 6; ++o)
                acc[i][j][o] += xv * w1[((o * 3 + ic) * 5 + ky) * 5 + kx];
            }
        }
    }
    float* P1q = &scr[q * SS + 1404];
#pragma unroll
    for (int o = 0; o < 6; ++o) {
      float v = fmaxf(acc[0][0][o], 0.f) + fmaxf(acc[0][1][o], 0.f)
              + fmaxf(acc[1][0][o], 0.f) + fmaxf(acc[1][1][o], 0.f);
      P1q[o * 66 + p] = 0.25f * v;
    }
  }

  // remainder: positions 58..65 of sample 3 as 32 unfused conv cells on wave 0
  if (tid < 32) {
    int pos = 58 + (tid >> 2), cell = tid & 3;
    int i2 = cell >> 1, j2 = cell & 1;
    int rp = pos / 6, cp = pos - rp * 6;
    int r2 = 2 * rp + i2, c2 = 2 * cp + j2;          // conv-output coords
    const float* Wq = &scr[3 * SS];
    float a6[6];
#pragma unroll
    for (int o = 0; o < 6; ++o) a6[o] = b1[o];
    for (int ic = 0; ic < 3; ++ic)
#pragma unroll
      for (int ky = 0; ky < 5; ++ky)
#pragma unroll
        for (int kx = 0; kx < 5; ++kx) {
          float xv = Wq[ic * 468 + (r2 + ky) * 18 + c2 + kx + 2];
#pragma unroll
          for (int o = 0; o < 6; ++o)
            a6[o] += xv * w1[((o * 3 + ic) * 5 + ky) * 5 + kx];
        }
#pragma unroll
    for (int o = 0; o < 6; ++o) {
      float v = fmaxf(a6[o], 0.f);
      v += __shfl_xor(v, 1, 64);
      v += __shfl_xor(v, 2, 64);
      a6[o] = v;
    }
    if (cell == 0) {
#pragma unroll
      for (int o = 0; o < 6; ++o)
        scr[3 * SS + 1404 + o * 66 + pos] = 0.25f * a6[o];
    }
  }
  __syncthreads();

  // ---------------- Phase C: tail, wave 0 only ----------------
  if (tid < 64) {
    // conv2+relu: 12 needed cells (rows 0..5, cols 0..1) x 4 samples = 48 lanes
    if (tid < 48) {
      int q = tid / 12, p = tid - q * 12;
      int r = p >> 1, c = p & 1;
      const float* P1q = &scr[q * SS + 1404];
      float acc[16];
#pragma unroll
      for (int o = 0; o < 16; ++o) acc[o] = b2w[o];
      for (int ic = 0; ic < 6; ++ic)
#pragma unroll
        for (int kr = 0; kr < 5; ++kr) {
          float xv[5];
#pragma unroll
          for (int kc = 0; kc < 5; ++kc)
            xv[kc] = P1q[ic * 66 + (r + kr) * 6 + c + kc];
#pragma unroll
          for (int kc = 0; kc < 5; ++kc)
#pragma unroll
            for (int o = 0; o < 16; ++o)
              acc[o] += xv[kc] * w2[((o * 6 + ic) * 5 + kr) * 5 + kc];
        }
      float* C2q = &scr[q * SS];
#pragma unroll
      for (int o = 0; o < 16; ++o) C2q[o * 12 + p] = fmaxf(acc[o], 0.f);
    }
    __builtin_amdgcn_wave_barrier();

    // pool2: (16,3) per sample
    for (int idx = tid; idx < 192; idx += 64) {
      int q = idx / 48, rem = idx - q * 48;
      int o = rem / 3, pr = rem - o * 3;
      const float* C2q = &scr[q * SS];
      float v = 0.25f * (C2q[o * 12 + 4 * pr] + C2q[o * 12 + 4 * pr + 1]
                       + C2q[o * 12 + 4 * pr + 2] + C2q[o * 12 + 4 * pr + 3]);
      scr[q * SS + 192 + o * 3 + pr] = v;
    }
    __builtin_amdgcn_wave_barrier();

    // conv3+relu: 64 out, per-sample pass (P2 reads broadcast)
    for (int q = 0; q < 4; ++q) {
      int o = tid;
      const float* P2q = &scr[q * SS + 192];
      float acc = b3[o];
#pragma unroll
      for (int k = 0; k < 48; ++k) acc += P2q[k] * w3[o * 48 + k];
      scr[q * SS + 240 + o] = fmaxf(acc, 0.f);
    }
    __builtin_amdgcn_wave_barrier();

    // fc1+relu -> B2 + out[64..96)
    for (int idx = tid; idx < 128; idx += 64) {
      int q = idx >> 5, j = idx & 31;
      const float* C3q = &scr[q * SS + 240];
      float acc = bf1[j];
#pragma unroll
      for (int k = 0; k < 64; ++k) acc += C3q[k] * wf1[j * 64 + k];
      acc = fmaxf(acc, 0.f);
      scr[q * SS + 304 + j] = acc;
      out[(size_t)(bb + q) * 96 + 64 + j] = acc;
    }
    __builtin_amdgcn_wave_barrier();

    // v = ipw[64:96] @ b2 + ipb[64:96]
    for (int idx = tid; idx < 128; idx += 64) {
      int q = idx >> 5, j = idx & 31;
      float acc = ipb[64 + j];
#pragma unroll
      for (int k = 0; k < 32; ++k) acc += scr[q * SS + 304 + k] * ipw[(64 + j) * 32 + k];
      scr[q * SS + 336 + j] = acc;
    }
    __builtin_amdgcn_wave_barrier();

    // a_mean = opw @ v + opb -> out[32..64)
    for (int idx = tid; idx < 128; idx += 64) {
      int q = idx >> 5, j = idx & 31;
      float acc = opb[j];
#pragma unroll
      for (int k = 0; k < 32; ++k) acc += scr[q * SS + 336 + k] * opw[j * 32 + k];
      out[(size_t)(bb + q) * 96 + 32 + j] = acc;
    }

    // xf = relu(t[:, :8] @ fc_w.T + fc_b) -> out[0..32)
    for (int idx = tid; idx < 128; idx += 64) {
      int q = idx >> 5, j = idx & 31;
      const int* tr = t + (size_t)(bb + q) * 232;
      float acc = fcb[j];
#pragma unroll
      for (int k = 0; k < 8; ++k) acc += (float)tr[k] * fcw[j * 8 + k];
      out[(size_t)(bb + q) * 96 + j] = fmaxf(acc, 0.f);
    }
  }
}

extern "C" void kernel_launch(void* const* d_in, const int* in_sizes, int n_in,
                              void* d_out, int out_size, void* d_ws, size_t ws_size,
                              hipStream_t stream) {
  const int*   t   = (const int*)d_in[0];
  const int*   pt  = (const int*)d_in[1];
  const float* w1  = (const float*)d_in[2];
  const float* b1  = (const float*)d_in[3];
  const float* w2  = (const float*)d_in[4];
  const float* b2w = (const float*)d_in[5];
  const float* w3  = (const float*)d_in[6];
  const float* b3  = (const float*)d_in[7];
  const float* wf1 = (const float*)d_in[8];
  const float* bf1 = (const float*)d_in[9];
  const float* fcw = (const float*)d_in[10];
  const float* fcb = (const float*)d_in[11];
  // d_in[12] = emb : dead (softmax over singleton axis == 1)
  const float* ipw = (const float*)d_in[13];
  const float* ipb = (const float*)d_in[14];
  const float* opw = (const float*)d_in[15];
  const float* opb = (const float*)d_in[16];

  float* out       = (float*)d_out;
  float* out_board = out + (size_t)BATCH * 96;

  hipLaunchKernelGGL(board_model_kernel, dim3(NBLK), dim3(256), 0, stream,
                     t, pt, w1, b1, w2, b2w, w3, b3, wf1, bf1, fcw, fcb,
                     ipw, ipb, opw, opb, out, out_board);
}

// Round 3
// 202.355 us; speedup vs baseline: 1.7751x; 1.7435x over previous
//
#include <hip/hip_runtime.h>
#include <cstddef>

// BoardModel: B=16384. out = [xf(32), a_mean(32), b2(32)] per sample, then board (3,22,12).
// MHA is degenerate (kv len 1 -> softmax==1): a_mean = out_proj(in_proj[64:96] @ b2 + b).
//
// R3: (a) rolling-row conv1 (live set ~45 VGPR, no spills) + launch_bounds(256,4);
//     (b) Phase C distributed: conv2 by out-channel-block per wave (scalar weights via
//         readfirstlane), then per-wave tail (wave q = sample q), per-lane vector
//         weight loads (L1-hot) for conv3/fc1/proj.

#define BATCH 16384
#define SPB   4
#define NBLK  (BATCH / SPB)
#define SS    1804   // per-sample scratch floats: SBE 3*26*18=1404 @0, P1 6*66=396 @1404.
                     // Tail overlays SBE: C2 192 @0, P2 48 @192, C3 64 @240, B2 32 @304, V 32 @336.

__global__ __launch_bounds__(256, 4)
void board_model_kernel(const int* __restrict__ t,           // (B,232)
                        const int* __restrict__ piece_table, // (8,4,4,4)
                        const float* __restrict__ w1, const float* __restrict__ b1,
                        const float* __restrict__ w2, const float* __restrict__ b2w,
                        const float* __restrict__ w3, const float* __restrict__ b3,
                        const float* __restrict__ wf1, const float* __restrict__ bf1,
                        const float* __restrict__ fcw, const float* __restrict__ fcb,
                        const float* __restrict__ ipw, const float* __restrict__ ipb,
                        const float* __restrict__ opw, const float* __restrict__ opb,
                        float* __restrict__ out,              // (B,96)
                        float* __restrict__ out_board)        // (B,3,22,12)
{
  __shared__ __align__(16) float scr[SPB * SS];

  const int tid  = threadIdx.x;
  const int lane = tid & 63;
  const int wv   = tid >> 6;          // wave id == sample slot
  const int bb   = blockIdx.x * SPB;

  // ---------------- Phase A: per-wave board build + board output ----------------
  {
    float* W = &scr[wv * SS];
    const int* tr = t + (size_t)(bb + wv) * 232;

    float4* W4 = (float4*)W;
    for (int i = lane; i < 351; i += 64) W4[i] = float4{0.f, 0.f, 0.f, 0.f};

    for (int i = lane; i < 210; i += 64) {
      int r = i / 10, b = i - r * 10;
      W[(r + 2) * 18 + b + 5] = (float)tr[22 + i];
    }

    for (int i = lane; i < 162; i += 64) {
      int ch = i / 54, k = i - ch * 54;
      int rr, cc;
      if (k < 12)      { rr = 23;         cc = k + 4; }
      else if (k < 33) { rr = k - 12 + 2; cc = 4; }
      else             { rr = k - 33 + 2; cc = 15; }
      W[ch * 468 + rr * 18 + cc] = 1.f;
    }

    if (lane < 4) {
      const int* pt = piece_table + (tr[8] * 4 + tr[4]) * 16;
      int sel = -1, n1 = 0;
#pragma unroll
      for (int j = 0; j < 16; ++j) { if (pt[j]) { if (n1 == lane) sel = j; ++n1; } }
      if (sel < 0) {
        int n0 = 0, want = lane - n1;
#pragma unroll
        for (int j = 0; j < 16; ++j) if (!pt[j]) { if (n0 == want) { sel = j; break; } ++n0; }
      }
      int cy = sel >> 2, cx = sel & 3;
      int x  = cx + tr[1] - 2;
      int y  = cy + tr[2];
      int ny = y + tr[3];
      if (y >= 0 && ny >= 0) {
        if (y  < 21 && x >= 0 && x < 10) W[468 + (y  + 2) * 18 + x + 5] = 1.f;
        if (ny < 21 && x >= 0 && x < 10) W[936 + (ny + 2) * 18 + x + 5] = 1.f;
      }
    }
    __builtin_amdgcn_wave_barrier();

    float* ob = out_board + (size_t)(bb + wv) * 792;
    for (int v = lane; v < 198; v += 64) {
      int j0 = v * 4;
      int ch = j0 / 264, rem = j0 - ch * 264;
      int r = rem / 12, c = rem - r * 12;
      const float* src = &W[ch * 468 + (r + 2) * 18 + c + 4];
      float4 val{src[0], src[1], src[2], src[3]};
      *(float4*)(ob + j0) = val;
    }
  }
  __syncthreads();

  // ---------------- Phase B: fused conv1+relu+pool1, rolling-row ----------------
  {
    int g = tid;                            // pool position 0..255 of 264
    int q = g / 66, p = g - q * 66;
    int r = p / 6, c = p - r * 6;
    const float* base0 = &scr[q * SS] + (2 * r) * 18 + (2 * c + 2);
    float acc[2][2][6];
#pragma unroll
    for (int i = 0; i < 2; ++i)
#pragma unroll
      for (int j = 0; j < 2; ++j)
#pragma unroll
        for (int o = 0; o < 6; ++o) acc[i][j][o] = b1[o];

    for (int ic = 0; ic < 3; ++ic) {
      const float* base = base0 + ic * 468;
#pragma unroll
      for (int u = 0; u < 6; ++u) {          // input row 2r+u; live: 6 floats
        float2 a0 = *(const float2*)(base + u * 18);
        float2 a1 = *(const float2*)(base + u * 18 + 2);
        float2 a2 = *(const float2*)(base + u * 18 + 4);
        float rv[6] = {a0.x, a0.y, a1.x, a1.y, a2.x, a2.y};
#pragma unroll
        for (int i = 0; i < 2; ++i) {
          if (u - i < 0 || u - i > 4) continue;   // folds at compile time
          const int ky = u - i;
#pragma unroll
          for (int j = 0; j < 2; ++j)
#pragma unroll
            for (int kx = 0; kx < 5; ++kx) {
              float xv = rv[j + kx];
#pragma unroll
              for (int o = 0; o < 6; ++o)
                acc[i][j][o] += xv * w1[((o * 3 + ic) * 5 + ky) * 5 + kx];
            }
        }
      }
    }
    float* P1q = &scr[q * SS + 1404];
#pragma unroll
    for (int o = 0; o < 6; ++o) {
      float v = fmaxf(acc[0][0][o], 0.f) + fmaxf(acc[0][1][o], 0.f)
              + fmaxf(acc[1][0][o], 0.f) + fmaxf(acc[1][1][o], 0.f);
      P1q[o * 66 + p] = 0.25f * v;
    }
  }

  // remainder: positions 58..65 of sample 3 as 32 unfused conv cells on wave 0
  if (tid < 32) {
    int pos = 58 + (tid >> 2), cell = tid & 3;
    int i2 = cell >> 1, j2 = cell & 1;
    int rp = pos / 6, cp = pos - rp * 6;
    int r2 = 2 * rp + i2, c2 = 2 * cp + j2;
    const float* Wq = &scr[3 * SS];
    float a6[6];
#pragma unroll
    for (int o = 0; o < 6; ++o) a6[o] = b1[o];
    for (int ic = 0; ic < 3; ++ic)
#pragma unroll
      for (int ky = 0; ky < 5; ++ky)
#pragma unroll
        for (int kx = 0; kx < 5; ++kx) {
          float xv = Wq[ic * 468 + (r2 + ky) * 18 + c2 + kx + 2];
#pragma unroll
          for (int o = 0; o < 6; ++o)
            a6[o] += xv * w1[((o * 3 + ic) * 5 + ky) * 5 + kx];
        }
#pragma unroll
    for (int o = 0; o < 6; ++o) {
      float v = fmaxf(a6[o], 0.f);
      v += __shfl_xor(v, 1, 64);
      v += __shfl_xor(v, 2, 64);
      a6[o] = v;
    }
    if (cell == 0) {
#pragma unroll
      for (int o = 0; o < 6; ++o)
        scr[3 * SS + 1404 + o * 66 + pos] = 0.25f * a6[o];
    }
  }
  __syncthreads();

  // ---------------- Phase C: distributed tail ----------------
  const int wvu = __builtin_amdgcn_readfirstlane(wv);   // wave-uniform for SGPR weights

  // conv2+relu: wave wvu computes out-channels [4*wvu,4*wvu+4) for all 4 samples
  if (lane < 48) {
    int q = lane / 12, p = lane - q * 12;
    int r = p >> 1, c = p & 1;
    const float* P1q = &scr[q * SS + 1404];
    float a4[4];
#pragma unroll
    for (int oo = 0; oo < 4; ++oo) a4[oo] = b2w[4 * wvu + oo];
    for (int ic = 0; ic < 6; ++ic)
#pragma unroll
      for (int kr = 0; kr < 5; ++kr) {
        float xv[5];
#pragma unroll
        for (int kc = 0; kc < 5; ++kc)
          xv[kc] = P1q[ic * 66 + (r + kr) * 6 + c + kc];
#pragma unroll
        for (int kc = 0; kc < 5; ++kc)
#pragma unroll
          for (int oo = 0; oo < 4; ++oo)
            a4[oo] += xv[kc] * w2[(((4 * wvu + oo) * 6 + ic) * 5 + kr) * 5 + kc];
      }
    float* C2q = &scr[q * SS];
#pragma unroll
    for (int oo = 0; oo < 4; ++oo)
      C2q[(4 * wvu + oo) * 12 + p] = fmaxf(a4[oo], 0.f);
  }
  __syncthreads();

  // per-wave tail: wave q owns sample q; no cross-wave deps from here on
  {
    const int q = wvu;
    float* S = &scr[q * SS];

    // pool2: 48 lanes -> P2[o*3+pr]
    if (lane < 48) {
      int o = lane / 3, pr = lane - o * 3;
      float v = 0.25f * (S[o * 12 + 4 * pr] + S[o * 12 + 4 * pr + 1]
                       + S[o * 12 + 4 * pr + 2] + S[o * 12 + 4 * pr + 3]);
      S[192 + lane] = v;
    }
    __builtin_amdgcn_wave_barrier();

    // conv3+relu: lane = out channel; per-lane weight row (L1-hot)
    {
      int o = lane;
      float acc = b3[o];
#pragma unroll
      for (int k = 0; k < 48; ++k) acc += S[192 + k] * w3[o * 48 + k];
      S[240 + o] = fmaxf(acc, 0.f);
    }
    __builtin_amdgcn_wave_barrier();

    // fc1+relu: j=lane&31, k-half split + shfl combine
    {
      int j = lane & 31, h = lane >> 5;
      float part = 0.f;
#pragma unroll
      for (int kk = 0; kk < 32; ++kk) {
        int k = 32 * h + kk;
        part += S[240 + k] * wf1[j * 64 + k];
      }
      part += __shfl_xor(part, 32, 64);
      if (h == 0) {
        float acc = fmaxf(bf1[j] + part, 0.f);
        S[304 + j] = acc;
        out[(size_t)(bb + q) * 96 + 64 + j] = acc;
      }
    }
    __builtin_amdgcn_wave_barrier();

    // lanes 0..31: v = ipw[64:96] @ b2 + ipb ; lanes 32..63: xf (independent)
    {
      int j = lane & 31;
      if (lane < 32) {
        float acc = ipb[64 + j];
#pragma unroll
        for (int k = 0; k < 32; ++k) acc += S[304 + k] * ipw[(64 + j) * 32 + k];
        S[336 + j] = acc;
      } else {
        const int* tr = t + (size_t)(bb + q) * 232;
        float acc = fcb[j];
#pragma unroll
        for (int k = 0; k < 8; ++k) acc += (float)tr[k] * fcw[j * 8 + k];
        out[(size_t)(bb + q) * 96 + j] = fmaxf(acc, 0.f);
      }
    }
    __builtin_amdgcn_wave_barrier();

    // a_mean = opw @ v + opb
    if (lane < 32) {
      int j = lane;
      float acc = opb[j];
#pragma unroll
      for (int k = 0; k < 32; ++k) acc += S[336 + k] * opw[j * 32 + k];
      out[(size_t)(bb + q) * 96 + 32 + j] = acc;
    }
  }
}

extern "C" void kernel_launch(void* const* d_in, const int* in_sizes, int n_in,
                              void* d_out, int out_size, void* d_ws, size_t ws_size,
                              hipStream_t stream) {
  const int*   t   = (const int*)d_in[0];
  const int*   pt  = (const int*)d_in[1];
  const float* w1  = (const float*)d_in[2];
  const float* b1  = (const float*)d_in[3];
  const float* w2  = (const float*)d_in[4];
  const float* b2w = (const float*)d_in[5];
  const float* w3  = (const float*)d_in[6];
  const float* b3  = (const float*)d_in[7];
  const float* wf1 = (const float*)d_in[8];
  const float* bf1 = (const float*)d_in[9];
  const float* fcw = (const float*)d_in[10];
  const float* fcb = (const float*)d_in[11];
  // d_in[12] = emb : dead (softmax over singleton axis == 1)
  const float* ipw = (const float*)d_in[13];
  const float* ipb = (const float*)d_in[14];
  const float* opw = (const float*)d_in[15];
  const float* opb = (const float*)d_in[16];

  float* out       = (float*)d_out;
  float* out_board = out + (size_t)BATCH * 96;

  hipLaunchKernelGGL(board_model_kernel, dim3(NBLK), dim3(256), 0, stream,
                     t, pt, w1, b1, w2, b2w, w3, b3, wf1, bf1, fcw, fcb,
                     ipw, ipb, opw, opb, out, out_board);
}